// Round 1
// 197.578 us; speedup vs baseline: 1.0525x; 1.0525x over previous
//
#include <hip/hip_runtime.h>
#include <hip/hip_bf16.h>

// Cross-attention B=8, S_ENC=2048, S_DEC=1024, D=512, U=512.
// R10: (a) T2 XOR-swizzle on all GEMM LDS tiles: store chunk c^((r>>1)&3) at
// slot c via pre-swizzled global source (glds writes linearly), read at slot
// quad^((m16>>1)&3). Kills the 8-way ds_read_b128 bank conflict (4.85M cyc in
// proj). (b) proj BN=256 + same-XCD bx-pair mapping (bx tiles of one A-row-tile
// are nBy apart, nBy%8==0) to halve A re-streams and L2-hit the rest.
// score/pv keep R9 batch-pinned XCD mapping, gain only the swizzle.
//
// ws: qh [0,8M) | kh [8M,24M) | P [0,32M) (after score) | vt [32M,48M) |
//     S [48M,112M) fp32 | dech @48M (dead pre-S) | Wt @56M (dead pre-S) |
//     ench @112M (dead after proj)

typedef __attribute__((ext_vector_type(8))) _Float16 f16x8;
typedef __attribute__((ext_vector_type(4))) _Float16 f16x4;
typedef __attribute__((ext_vector_type(4))) float f32x4;

#define MFMA16(a, b, c) __builtin_amdgcn_mfma_f32_16x16x32_f16(a, b, c, 0, 0, 0)
#define L2E 1.44269504088896f

__device__ __forceinline__ void glds16(const void* g, void* l) {
    __builtin_amdgcn_global_load_lds(
        (const __attribute__((address_space(1))) void*)g,
        (__attribute__((address_space(3))) void*)l, 16, 0, 0);
}

// prep: blocks [0,4096) enc cvt, [4096,6144) dec cvt, [6144,6336) W transpose.
__global__ __launch_bounds__(256) void prep_kernel(
    const float* __restrict__ enc, const float* __restrict__ dec,
    const float* __restrict__ Wq, const float* __restrict__ Wk,
    const float* __restrict__ Wv, _Float16* __restrict__ oenc,
    _Float16* __restrict__ odec, _Float16* __restrict__ planes) {
    const int bid = blockIdx.x;
    if (bid < 6144) {
        const float* x;
        _Float16* o;
        size_t i;
        if (bid < 4096) { x = enc; o = oenc; i = ((size_t)bid * 256 + threadIdx.x) * 8; }
        else { x = dec; o = odec; i = ((size_t)(bid - 4096) * 256 + threadIdx.x) * 8; }
        float4 a0 = *(const float4*)(x + i);
        float4 a1 = *(const float4*)(x + i + 4);
        float v[8] = {a0.x, a0.y, a0.z, a0.w, a1.x, a1.y, a1.z, a1.w};
        f16x8 h;
#pragma unroll
        for (int j = 0; j < 8; ++j) h[j] = (_Float16)v[j];
        *(f16x8*)(o + i) = h;
        return;
    }
    const int t = bid - 6144;
    const int zw = t >> 6, r = t & 63;
    const int u0 = (r & 7) * 64, d0 = (r >> 3) * 64;
    const float* W = zw == 0 ? Wq : (zw == 1 ? Wk : Wv);
    _Float16* ot = planes + (size_t)zw * 262144;
    __shared__ float T[64][65];
    const int tr = threadIdx.x >> 4, tc = (threadIdx.x & 15) * 4;
#pragma unroll
    for (int j = 0; j < 4; ++j) {
        float4 vv = *(const float4*)(W + (size_t)(d0 + tr + j * 16) * 512 + u0 + tc);
        T[tr + j * 16][tc + 0] = vv.x;
        T[tr + j * 16][tc + 1] = vv.y;
        T[tr + j * 16][tc + 2] = vv.z;
        T[tr + j * 16][tc + 3] = vv.w;
    }
    __syncthreads();
#pragma unroll
    for (int j = 0; j < 4; ++j) {
        int ul = tr + j * 16;
        f16x4 h;
#pragma unroll
        for (int i = 0; i < 4; ++i) h[i] = (_Float16)T[tc + i][ul];
        *(f16x4*)(ot + (size_t)(u0 + ul) * 512 + d0 + tc) = h;
    }
}

// Unified projections (R10): 64x256 tiles, K=512, dbuf LDS, glds-16, swizzled.
// Grid 1280: seg0 [0,256) dec->qh (by=bid&127, bx=bid>>7), seg1 [256,768)
// enc->kh, seg2 [768,1280) enc->vt (by=local&255, bx=local>>8). bx pair of a
// given by is nBy apart (nBy%8==0) -> same XCD -> A-tile L2 reuse.
__global__ __launch_bounds__(256) void proj_kernel(
    const _Float16* __restrict__ dech, const _Float16* __restrict__ ench,
    const _Float16* __restrict__ wts, _Float16* __restrict__ qh,
    _Float16* __restrict__ kh, _Float16* __restrict__ vt) {
    __shared__ __align__(16) char smem[40960];
    const int bid = blockIdx.x;
    int seg, bx, by;
    if (bid < 256) { seg = 0; by = bid & 127; bx = bid >> 7; }
    else if (bid < 768) { int t = bid - 256; seg = 1; by = t & 255; bx = t >> 8; }
    else { int t = bid - 768; seg = 2; by = t & 255; bx = t >> 8; }
    const _Float16* A = seg == 0 ? dech : ench;
    const _Float16* Bp = wts + (size_t)seg * 262144;

    const int tid = threadIdx.x;
    const int wave = tid >> 6, lane = tid & 63;
    const int quad = lane >> 4, m16 = lane & 15;
    const int wr = wave >> 1, wc = wave & 1;
    const int row0 = by * 64, col0 = bx * 256;

    // source pre-swizzle: lane L feeds LDS slot (r=L>>2, c=L&3); slot c must
    // hold global chunk c ^ ((r>>1)&3) -> read chunk (L&3)^((L>>3)&3).
    const int scol = ((lane & 3) ^ ((lane >> 3) & 3)) * 8;
    const int srowA = wave * 16 + (lane >> 2);
    const int srowB = wave * 64 + (lane >> 2);
    const _Float16* agp = A + (size_t)(row0 + srowA) * 512 + scol;
    const _Float16* bgp = Bp + (size_t)(col0 + srowB) * 512 + scol;
    const int ldsAoff = wave * 1024;
    const int ldsBoff = 4096 + wave * 4096;

    f32x4 acc[2][8];
#pragma unroll
    for (int mt = 0; mt < 2; ++mt)
#pragma unroll
        for (int nt = 0; nt < 8; ++nt) acc[mt][nt] = (f32x4){0.f, 0.f, 0.f, 0.f};

    auto stage = [&](int i, int buf) {
        char* base = smem + buf * 20480;
        const int k0 = i * 32;
        glds16(agp + k0, base + ldsAoff);
#pragma unroll
        for (int j = 0; j < 4; ++j)
            glds16(bgp + k0 + j * 16 * 512, base + ldsBoff + j * 1024);
    };

    // swizzled read slot: chunk quad of row (…+m16) sits at slot quad^((m16>>1)&3)
    const int csw = (quad ^ ((lane >> 1) & 3)) * 16;

    stage(0, 0);
    for (int i = 0; i < 16; ++i) {
        __syncthreads();
        if (i + 1 < 16) stage(i + 1, (i + 1) & 1);
        const char* bb = smem + (i & 1) * 20480;
        const char* pa = bb + (wr * 32 + m16) * 64 + csw;
        const char* pb = bb + 4096 + (wc * 128 + m16) * 64 + csw;
        f16x8 af[2];
#pragma unroll
        for (int mt = 0; mt < 2; ++mt) af[mt] = *(const f16x8*)(pa + mt * 1024);
#pragma unroll
        for (int nt = 0; nt < 8; ++nt) {
            f16x8 bf = *(const f16x8*)(pb + nt * 1024);
#pragma unroll
            for (int mt = 0; mt < 2; ++mt) acc[mt][nt] = MFMA16(af[mt], bf, acc[mt][nt]);
        }
    }

    if (seg < 2) {
        _Float16* o = seg == 0 ? qh : kh;
#pragma unroll
        for (int mt = 0; mt < 2; ++mt)
#pragma unroll
            for (int nt = 0; nt < 8; ++nt)
#pragma unroll
                for (int rr = 0; rr < 4; ++rr) {
                    int row = row0 + wr * 32 + mt * 16 + quad * 4 + rr;
                    int col = col0 + wc * 128 + nt * 16 + m16;
                    o[(size_t)row * 512 + col] = (_Float16)acc[mt][nt][rr];
                }
    } else {
        __syncthreads();
        char* reg = smem + wave * 8192;  // [128 n][32 m] fp16 per-wave scratch
#pragma unroll
        for (int nt = 0; nt < 8; ++nt)
#pragma unroll
            for (int mt = 0; mt < 2; ++mt) {
                f16x4 pk;
#pragma unroll
                for (int rr = 0; rr < 4; ++rr) pk[rr] = (_Float16)acc[mt][nt][rr];
                *(f16x4*)(reg + (nt * 16 + m16) * 64 + (mt * 16 + quad * 4) * 2) = pk;
            }
        const int b = row0 >> 11;
        const int s_base = (row0 & 2047) + wr * 32;
        const int u_base = col0 + wc * 128;
#pragma unroll
        for (int j = 0; j < 8; ++j) {
            int n = j * 16 + (lane >> 2);
            int mo = (lane & 3) * 8;
            f16x8 val = *(const f16x8*)(reg + n * 64 + mo * 2);
            *(f16x8*)(vt + (size_t)(b * 512 + u_base + n) * 2048 + s_base + mo) = val;
        }
    }
}

// Score GEMM, 128x128 tiles, batch-pinned: b = blockIdx.x (1024 blocks),
// z = b&7 (XCD), r = b>>3: y = r>>4 (q-tile), x = r&15 (s-tile). Swizzled LDS.
__global__ __launch_bounds__(256) void score_kernel(
    const _Float16* __restrict__ qh, const _Float16* __restrict__ kh,
    float* __restrict__ S) {
    __shared__ __align__(16) char smem[32768];
    const int b = blockIdx.x;
    const int z = b & 7, r = b >> 3;
    const int by = r >> 4, bx = r & 15;
    const int tid = threadIdx.x;
    const int wave = tid >> 6, lane = tid & 63;
    const int quad = lane >> 4, m16 = lane & 15;
    const int wr = wave >> 1, wc = wave & 1;
    const int row0 = z * 1024 + by * 128;
    const int col0 = bx * 128;

    const int scol = ((lane & 3) ^ ((lane >> 3) & 3)) * 8;
    const int srow = wave * 32 + (lane >> 2);
    const _Float16* agp = qh + (size_t)(row0 + srow) * 512 + scol;
    const _Float16* bgp = kh + (size_t)(z * 2048 + col0 + srow) * 512 + scol;
    const int ldsAoff = wave * 2048;
    const int ldsBoff = 8192 + wave * 2048;

    f32x4 acc[4][4];
#pragma unroll
    for (int mt = 0; mt < 4; ++mt)
#pragma unroll
        for (int nt = 0; nt < 4; ++nt) acc[mt][nt] = (f32x4){0.f, 0.f, 0.f, 0.f};

    auto stage = [&](int i, int buf) {
        char* base = smem + buf * 16384;
        const int k0 = i * 32;
#pragma unroll
        for (int j = 0; j < 2; ++j) {
            glds16(agp + k0 + j * 16 * 512, base + ldsAoff + j * 1024);
            glds16(bgp + k0 + j * 16 * 512, base + ldsBoff + j * 1024);
        }
    };

    const int csw = (quad ^ ((lane >> 1) & 3)) * 16;

    stage(0, 0);
    for (int i = 0; i < 16; ++i) {
        __syncthreads();
        if (i + 1 < 16) stage(i + 1, (i + 1) & 1);
        const char* bb = smem + (i & 1) * 16384;
        const char* pa = bb + (wr * 64 + m16) * 64 + csw;
        const char* pb = bb + 8192 + (wc * 64 + m16) * 64 + csw;
        f16x8 af[4];
#pragma unroll
        for (int mt = 0; mt < 4; ++mt) af[mt] = *(const f16x8*)(pa + mt * 1024);
#pragma unroll
        for (int nt = 0; nt < 4; ++nt) {
            f16x8 bf = *(const f16x8*)(pb + nt * 1024);
#pragma unroll
            for (int mt = 0; mt < 4; ++mt) acc[mt][nt] = MFMA16(af[mt], bf, acc[mt][nt]);
        }
    }
#pragma unroll
    for (int mt = 0; mt < 4; ++mt)
#pragma unroll
        for (int nt = 0; nt < 4; ++nt)
#pragma unroll
            for (int rr = 0; rr < 4; ++rr) {
                int row = row0 + wr * 64 + mt * 16 + quad * 4 + rr;
                int col = col0 + wc * 64 + nt * 16 + m16;
                S[(size_t)row * 2048 + col] = acc[mt][nt][rr];
            }
}

// Row softmax over 2048 cols, fp32 in -> fp16 out (normalized). One block/row.
__global__ __launch_bounds__(256) void softmax_kernel(const float* __restrict__ S,
                                                      _Float16* __restrict__ P) {
    const int row = blockIdx.x;
    const int tid = threadIdx.x;
    const int wave = tid >> 6, lane = tid & 63;
    __shared__ float red[8];

    const float* sp = S + (size_t)row * 2048 + tid * 8;
    float4 x0 = *(const float4*)sp;
    float4 x1 = *(const float4*)(sp + 4);
    float v[8] = {x0.x, x0.y, x0.z, x0.w, x1.x, x1.y, x1.z, x1.w};

    float mx = v[0];
#pragma unroll
    for (int i = 1; i < 8; ++i) mx = fmaxf(mx, v[i]);
#pragma unroll
    for (int off = 32; off > 0; off >>= 1) mx = fmaxf(mx, __shfl_down(mx, off));
    if (lane == 0) red[wave] = mx;
    __syncthreads();
    if (tid == 0) red[4] = fmaxf(fmaxf(red[0], red[1]), fmaxf(red[2], red[3]));
    __syncthreads();
    mx = red[4];

    float e[8];
    float sum = 0.f;
#pragma unroll
    for (int i = 0; i < 8; ++i) {
        e[i] = exp2f((v[i] - mx) * L2E);
        sum += e[i];
    }
#pragma unroll
    for (int off = 32; off > 0; off >>= 1) sum += __shfl_down(sum, off);
    if (lane == 0) red[wave] = sum;
    __syncthreads();
    if (tid == 0) red[5] = red[0] + red[1] + red[2] + red[3];
    __syncthreads();
    float inv = 1.0f / red[5];

    f16x8 ov;
#pragma unroll
    for (int i = 0; i < 8; ++i) ov[i] = (_Float16)(e[i] * inv);
    *(f16x8*)(P + (size_t)row * 2048 + tid * 8) = ov;
}

// PV GEMM, 64 q x 128 u tiles, batch-pinned: b = blockIdx.x (512 blocks),
// z = b&7 (XCD -> vt[z] 2 MB stays L2-resident), r = b>>3: y = r>>2 (q-tile,
// outer so P streams in 256 KB slabs), x = r&3 (u-slab). Swizzled LDS.
__global__ __launch_bounds__(256) void pv_kernel(
    const _Float16* __restrict__ P, const _Float16* __restrict__ vt,
    float* __restrict__ out) {
    __shared__ __align__(16) char smem[24576];
    const int b = blockIdx.x;
    const int z = b & 7, r = b >> 3;
    const int by = r >> 2, bx = r & 3;
    const int tid = threadIdx.x;
    const int wave = tid >> 6, lane = tid & 63;
    const int quad = lane >> 4, m16 = lane & 15;
    const int wr = wave >> 1, wc = wave & 1;
    const int row0 = z * 1024 + by * 64;
    const int col0 = bx * 128;

    const int scol = ((lane & 3) ^ ((lane >> 3) & 3)) * 8;
    const int srowA = wave * 16 + (lane >> 2);
    const int srowB = wave * 32 + (lane >> 2);
    const _Float16* agp = P + (size_t)(row0 + srowA) * 2048 + scol;
    const _Float16* bgp = vt + (size_t)(z * 512 + col0 + srowB) * 2048 + scol;
    const int ldsAoff = wave * 1024;
    const int ldsBoff = 4096 + wave * 2048;

    f32x4 acc[2][4];
#pragma unroll
    for (int mt = 0; mt < 2; ++mt)
#pragma unroll
        for (int nt = 0; nt < 4; ++nt) acc[mt][nt] = (f32x4){0.f, 0.f, 0.f, 0.f};

    auto stage = [&](int i, int buf) {
        char* base = smem + buf * 12288;
        const int k0 = i * 32;
        glds16(agp + k0, base + ldsAoff);
#pragma unroll
        for (int j = 0; j < 2; ++j)
            glds16(bgp + k0 + j * 16 * 2048, base + ldsBoff + j * 1024);
    };

    const int csw = (quad ^ ((lane >> 1) & 3)) * 16;

    stage(0, 0);
    for (int i = 0; i < 64; ++i) {
        __syncthreads();
        if (i + 1 < 64) stage(i + 1, (i + 1) & 1);
        const char* bb = smem + (i & 1) * 12288;
        const char* pa = bb + (wr * 32 + m16) * 64 + csw;
        const char* pb = bb + 4096 + (wc * 64 + m16) * 64 + csw;
        f16x8 af[2];
#pragma unroll
        for (int mt = 0; mt < 2; ++mt) af[mt] = *(const f16x8*)(pa + mt * 1024);
#pragma unroll
        for (int nt = 0; nt < 4; ++nt) {
            f16x8 bf = *(const f16x8*)(pb + nt * 1024);
#pragma unroll
            for (int mt = 0; mt < 2; ++mt) acc[mt][nt] = MFMA16(af[mt], bf, acc[mt][nt]);
        }
    }

#pragma unroll
    for (int mt = 0; mt < 2; ++mt)
#pragma unroll
        for (int nt = 0; nt < 4; ++nt)
#pragma unroll
            for (int rr = 0; rr < 4; ++rr) {
                int row = row0 + wr * 32 + mt * 16 + quad * 4 + rr;
                int col = col0 + wc * 64 + nt * 16 + m16;
                out[(size_t)row * 512 + col] = acc[mt][nt][rr];
            }
}

extern "C" void kernel_launch(void* const* d_in, const int* in_sizes, int n_in,
                              void* d_out, int out_size, void* d_ws, size_t ws_size,
                              hipStream_t stream) {
    const float* enc = (const float*)d_in[0];  // [8,2048,512]
    const float* dec = (const float*)d_in[1];  // [8,1024,512]
    const float* Wq = (const float*)d_in[2];   // [512,512]
    const float* Wk = (const float*)d_in[3];
    const float* Wv = (const float*)d_in[4];
    float* out = (float*)d_out;                // [8,1024,512] fp32

    char* ws = (char*)d_ws;
    _Float16* qh = (_Float16*)(ws);
    _Float16* kh = (_Float16*)(ws + ((size_t)8 << 20));
    _Float16* P = (_Float16*)(ws);                          // aliases qh/kh after score
    _Float16* vt = (_Float16*)(ws + ((size_t)32 << 20));
    float* S = (float*)(ws + ((size_t)48 << 20));
    _Float16* dech = (_Float16*)(ws + ((size_t)48 << 20));  // dead before S written
    _Float16* wts = (_Float16*)(ws + ((size_t)56 << 20));   // dead before S written
    _Float16* ench = (_Float16*)(ws + ((size_t)112 << 20)); // dead after proj

    dim3 blk(256);
    prep_kernel<<<6336, blk, 0, stream>>>(enc, dec, Wq, Wk, Wv, ench, dech, wts);
    proj_kernel<<<1280, blk, 0, stream>>>(dech, ench, wts, qh, kh, vt);
    score_kernel<<<1024, blk, 0, stream>>>(qh, kh, S);
    softmax_kernel<<<8192, blk, 0, stream>>>(S, P);
    pv_kernel<<<512, blk, 0, stream>>>(P, vt, out);
}